// Round 10
// baseline (160.268 us; speedup 1.0000x reference)
//
#include <hip/hip_runtime.h>
#include <hip/hip_bf16.h>
#include <math.h>

#define NQ   4096
#define DIMC 256
#define NHC  8
#define NPC  8
#define HDC  32
#define HC   64
#define WC   64
#define BC   4
#define LSTR 40    // small LDS row stride (ushorts): 80 B
#define KSTR 264   // full-K A-tile row stride (ushorts): 528 B -> 2-way banks

typedef __bf16 bf16x8 __attribute__((ext_vector_type(8)));
typedef __attribute__((ext_vector_type(4))) float f4;
typedef __attribute__((ext_vector_type(8))) short s8v;

__device__ __forceinline__ ushort f2bf(float f) {
  __hip_bfloat16 h = __float2bfloat16(f);
  union { __hip_bfloat16 h; ushort u; } c; c.h = h; return c.u;
}
__device__ __forceinline__ float bfu2f(ushort u) {
  union { unsigned i; float f; } c; c.i = ((unsigned)u) << 16; return c.f;
}
__device__ __forceinline__ float bflo(unsigned u) {
  union { unsigned i; float f; } c; c.i = u << 16; return c.f;
}
__device__ __forceinline__ float bfhi(unsigned u) {
  union { unsigned i; float f; } c; c.i = u & 0xffff0000u; return c.f;
}

union bfr8 { ushort u[8]; bf16x8 v; s8v s; };

// ---------------------------------------------------------------------------
// k_proj (R8 verbatim, champion): y in [0,2] loc/att split-precision,
// y in [3,6] value projection. 64n x 64o, BK=32 register-prefetch pipeline.
// ---------------------------------------------------------------------------
__global__ __launch_bounds__(256) void k_proj(
    const float* __restrict__ query, const float* __restrict__ value,
    const float* __restrict__ W_loc, const float* __restrict__ b_loc,
    const float* __restrict__ W_att, const float* __restrict__ b_att,
    const float* __restrict__ W_val, const float* __restrict__ b_val,
    float* __restrict__ loc, float* __restrict__ att,
    ushort* __restrict__ vproj) {
  __shared__ __align__(16) ushort smem[4 * 64 * LSTR];  // 20.5 KB
  const int tid = threadIdx.x;
  const int b = blockIdx.z, n0 = blockIdx.x * 64;
  const int lane = tid & 63, wid = tid >> 6;
  const int wn0 = (wid & 1) * 32, wo0 = (wid >> 1) * 32;
  const int am = lane & 15, kq = (lane >> 4) * 8;
  const int an = tid & 63, ak = (tid >> 6) * 8;
  const int wo = tid >> 2, wk = (tid & 3) * 8;

  f4 acc[2][2];
#pragma unroll
  for (int mi = 0; mi < 2; ++mi) { acc[mi][0] = (f4)0.f; acc[mi][1] = (f4)0.f; }

  if (blockIdx.y < 3) {
    ushort* Ah = smem;
    ushort* Al = smem + 64 * LSTR;
    ushort* Wh = smem + 2 * 64 * LSTR;
    ushort* Wl = smem + 3 * 64 * LSTR;
    const int o0 = blockIdx.y * 64;
    const float* Xb = query + (size_t)b * DIMC * NQ + n0 + an;
    const int oo = o0 + wo;
    const float* Wrow = (oo < 128) ? (W_loc + (size_t)oo * DIMC)
                                   : (W_att + (size_t)(oo - 128) * DIMC);
    float ax[8];
    float4 wx0, wx1;
#pragma unroll
    for (int j = 0; j < 8; ++j) ax[j] = Xb[(size_t)(ak + j) * NQ];
    wx0 = *(const float4*)(Wrow + wk);
    wx1 = *(const float4*)(Wrow + wk + 4);

    for (int t = 0; t < 8; ++t) {
      __syncthreads();
      {
        bfr8 ph, pl;
#pragma unroll
        for (int j = 0; j < 8; ++j) {
          ushort h = f2bf(ax[j]);
          ph.u[j] = h;
          pl.u[j] = f2bf(ax[j] - bfu2f(h));
        }
        *(s8v*)(&Ah[an * LSTR + ak]) = ph.s;
        *(s8v*)(&Al[an * LSTR + ak]) = pl.s;
        float wt[8] = {wx0.x, wx0.y, wx0.z, wx0.w, wx1.x, wx1.y, wx1.z, wx1.w};
        bfr8 qh, ql;
#pragma unroll
        for (int j = 0; j < 8; ++j) {
          ushort h = f2bf(wt[j]);
          qh.u[j] = h;
          ql.u[j] = f2bf(wt[j] - bfu2f(h));
        }
        *(s8v*)(&Wh[wo * LSTR + wk]) = qh.s;
        *(s8v*)(&Wl[wo * LSTR + wk]) = ql.s;
      }
      if (t < 7) {
        const int k0 = (t + 1) * 32;
#pragma unroll
        for (int j = 0; j < 8; ++j) ax[j] = Xb[(size_t)(k0 + ak + j) * NQ];
        wx0 = *(const float4*)(Wrow + k0 + wk);
        wx1 = *(const float4*)(Wrow + k0 + wk + 4);
      }
      __syncthreads();
      bf16x8 ah[2], al[2], bh[2], bl[2];
#pragma unroll
      for (int mi = 0; mi < 2; ++mi) {
        ah[mi] = *(const bf16x8*)(&Ah[(wn0 + mi * 16 + am) * LSTR + kq]);
        al[mi] = *(const bf16x8*)(&Al[(wn0 + mi * 16 + am) * LSTR + kq]);
      }
#pragma unroll
      for (int oj = 0; oj < 2; ++oj) {
        bh[oj] = *(const bf16x8*)(&Wh[(wo0 + oj * 16 + am) * LSTR + kq]);
        bl[oj] = *(const bf16x8*)(&Wl[(wo0 + oj * 16 + am) * LSTR + kq]);
      }
#pragma unroll
      for (int mi = 0; mi < 2; ++mi)
#pragma unroll
        for (int oj = 0; oj < 2; ++oj) {
          acc[mi][oj] = __builtin_amdgcn_mfma_f32_16x16x32_bf16(ah[mi], bh[oj], acc[mi][oj], 0, 0, 0);
          acc[mi][oj] = __builtin_amdgcn_mfma_f32_16x16x32_bf16(al[mi], bh[oj], acc[mi][oj], 0, 0, 0);
          acc[mi][oj] = __builtin_amdgcn_mfma_f32_16x16x32_bf16(ah[mi], bl[oj], acc[mi][oj], 0, 0, 0);
        }
    }
    const bool isAtt = (o0 >= 128);
    float* dstBase = isAtt ? att : loc;
    const float* bias = isAtt ? b_att : b_loc;
    const int ostride = isAtt ? 64 : 128;
    const int ob = isAtt ? o0 - 128 : o0;
#pragma unroll
    for (int oj = 0; oj < 2; ++oj) {
      const int o = ob + wo0 + oj * 16 + am;
      const float bv = bias[o];
#pragma unroll
      for (int mi = 0; mi < 2; ++mi) {
        const int nb = n0 + wn0 + mi * 16 + (lane >> 4) * 4;
#pragma unroll
        for (int r = 0; r < 4; ++r)
          dstBase[((size_t)b * NQ + nb + r) * ostride + o] = acc[mi][oj][r] + bv;
      }
    }
  } else {
    ushort* As = smem;
    ushort* Ws = smem + 64 * LSTR;
    const int o0 = (blockIdx.y - 3) * 64;
    const float* Xb = value + (size_t)b * DIMC * NQ + n0 + an;
    const float* Wrow = W_val + (size_t)(o0 + wo) * DIMC;

    float ax[8];
    float4 wx0, wx1;
#pragma unroll
    for (int j = 0; j < 8; ++j) ax[j] = Xb[(size_t)(ak + j) * NQ];
    wx0 = *(const float4*)(Wrow + wk);
    wx1 = *(const float4*)(Wrow + wk + 4);

    for (int t = 0; t < 8; ++t) {
      __syncthreads();
      {
        bfr8 pa;
#pragma unroll
        for (int j = 0; j < 8; ++j) pa.u[j] = f2bf(ax[j]);
        *(s8v*)(&As[an * LSTR + ak]) = pa.s;
        float wt[8] = {wx0.x, wx0.y, wx0.z, wx0.w, wx1.x, wx1.y, wx1.z, wx1.w};
        bfr8 pw;
#pragma unroll
        for (int j = 0; j < 8; ++j) pw.u[j] = f2bf(wt[j]);
        *(s8v*)(&Ws[wo * LSTR + wk]) = pw.s;
      }
      if (t < 7) {
        const int k0 = (t + 1) * 32;
#pragma unroll
        for (int j = 0; j < 8; ++j) ax[j] = Xb[(size_t)(k0 + ak + j) * NQ];
        wx0 = *(const float4*)(Wrow + k0 + wk);
        wx1 = *(const float4*)(Wrow + k0 + wk + 4);
      }
      __syncthreads();
      bf16x8 af[2], bf[2];
#pragma unroll
      for (int mi = 0; mi < 2; ++mi)
        af[mi] = *(const bf16x8*)(&As[(wn0 + mi * 16 + am) * LSTR + kq]);
#pragma unroll
      for (int oj = 0; oj < 2; ++oj)
        bf[oj] = *(const bf16x8*)(&Ws[(wo0 + oj * 16 + am) * LSTR + kq]);
#pragma unroll
      for (int mi = 0; mi < 2; ++mi)
#pragma unroll
        for (int oj = 0; oj < 2; ++oj)
          acc[mi][oj] = __builtin_amdgcn_mfma_f32_16x16x32_bf16(af[mi], bf[oj], acc[mi][oj], 0, 0, 0);
    }
#pragma unroll
    for (int oj = 0; oj < 2; ++oj) {
      const int o = o0 + wo0 + oj * 16 + am;
      const int h = o >> 5, d = o & 31;
      const float bias = b_val[o];
      ushort* dst = vproj + ((size_t)(b * NHC + h) * NQ) * HDC + d;
#pragma unroll
      for (int mi = 0; mi < 2; ++mi) {
        const int nb = n0 + wn0 + mi * 16 + (lane >> 4) * 4;
#pragma unroll
        for (int r = 0; r < 4; ++r)
          dst[(size_t)(nb + r) * HDC] = f2bf(acc[mi][oj][r] + bias);
      }
    }
  }
}

// ---------------------------------------------------------------------------
// k_samout: FUSED sampling + out-GEMM. Block = 32-query tile, all heads.
// Phase A: (q,h,d8-group) tasks compute softmax+bilinear coefs in registers
// (4x redundancy across d-groups) and gather uint4 bf16 corners, writing
// results directly into the LDS A-tile (msda never touches HBM).
// Phase B: out = A(LDS) @ W_out^T + b_out, R8-style K-loop with W staged
// per K-step + register prefetch.
// ---------------------------------------------------------------------------
__global__ __launch_bounds__(256) void k_samout(
    const float* __restrict__ loc, const float* __restrict__ attL,
    const ushort* __restrict__ vproj,
    const float* __restrict__ W_out, const float* __restrict__ b_out,
    float* __restrict__ out) {
  __shared__ __align__(16) ushort As[32 * KSTR];   // 16.9 KB  (32n x 256k)
  __shared__ __align__(16) ushort Ws[256 * LSTR];  // 20.5 KB  (256o x 32k)
  const int tid = threadIdx.x, b = blockIdx.z, n0 = blockIdx.x * 32;

  // ---------------- Phase A: sampling into LDS A-tile ----------------
#pragma unroll
  for (int it = 0; it < 4; ++it) {
    const int task = it * 256 + tid;
    const int q = task >> 5, h = (task >> 2) & 7, dg = task & 3;
    const int n = n0 + q;
    const float* ap = attL + ((size_t)b * NQ + n) * 64 + h * 8;
    const float4 l0 = *(const float4*)(ap);
    const float4 l1 = *(const float4*)(ap + 4);
    float lg[8] = {l0.x, l0.y, l0.z, l0.w, l1.x, l1.y, l1.z, l1.w};
    float m = lg[0];
#pragma unroll
    for (int p = 1; p < 8; ++p) m = fmaxf(m, lg[p]);
    float s = 0.f;
#pragma unroll
    for (int p = 0; p < 8; ++p) { lg[p] = __expf(lg[p] - m); s += lg[p]; }
    const float inv = 1.0f / s;
    const float* lp = loc + ((size_t)b * NQ + n) * 128 + h * 16;
    float4 xy0 = *(const float4*)(lp);
    float4 xy1 = *(const float4*)(lp + 4);
    float4 xy2 = *(const float4*)(lp + 8);
    float4 xy3 = *(const float4*)(lp + 12);
    const float xyf[16] = {xy0.x, xy0.y, xy0.z, xy0.w, xy1.x, xy1.y, xy1.z, xy1.w,
                           xy2.x, xy2.y, xy2.z, xy2.w, xy3.x, xy3.y, xy3.z, xy3.w};
    const ushort* vb = vproj + ((size_t)(b * NHC + h) * NQ) * HDC + dg * 8;
    float a[8] = {};
#pragma unroll
    for (int p = 0; p < 8; ++p) {
      const float x = xyf[2 * p] * 64.0f - 0.5f;
      const float y = xyf[2 * p + 1] * 64.0f - 0.5f;
      const float x0f = floorf(x), y0f = floorf(y);
      const float wx = x - x0f, wy = y - y0f;
      const int x0 = (int)x0f, y0 = (int)y0f;
      const int x1 = x0 + 1, y1 = y0 + 1;
      const float fx0 = (x0 >= 0 && x0 < WC) ? 1.f : 0.f;
      const float fx1 = (x1 >= 0 && x1 < WC) ? 1.f : 0.f;
      const float fy0 = (y0 >= 0 && y0 < HC) ? 1.f : 0.f;
      const float fy1 = (y1 >= 0 && y1 < HC) ? 1.f : 0.f;
      const int cx0 = min(max(x0, 0), WC - 1), cx1 = min(max(x1, 0), WC - 1);
      const int cy0 = min(max(y0, 0), HC - 1), cy1 = min(max(y1, 0), HC - 1);
      const float w = lg[p] * inv;
      const float c00 = w * (1.f - wx) * (1.f - wy) * fx0 * fy0;
      const float c01 = w * wx * (1.f - wy) * fx1 * fy0;
      const float c10 = w * (1.f - wx) * wy * fx0 * fy1;
      const float c11 = w * wx * wy * fx1 * fy1;
      const uint4 u00 = *(const uint4*)(vb + (cy0 * WC + cx0) * HDC);
      const uint4 u01 = *(const uint4*)(vb + (cy0 * WC + cx1) * HDC);
      const uint4 u10 = *(const uint4*)(vb + (cy1 * WC + cx0) * HDC);
      const uint4 u11 = *(const uint4*)(vb + (cy1 * WC + cx1) * HDC);
      const unsigned g00[4] = {u00.x, u00.y, u00.z, u00.w};
      const unsigned g01[4] = {u01.x, u01.y, u01.z, u01.w};
      const unsigned g10[4] = {u10.x, u10.y, u10.z, u10.w};
      const unsigned g11[4] = {u11.x, u11.y, u11.z, u11.w};
#pragma unroll
      for (int j = 0; j < 4; ++j) {
        a[2 * j]     += c00 * bflo(g00[j]) + c01 * bflo(g01[j]) + c10 * bflo(g10[j]) + c11 * bflo(g11[j]);
        a[2 * j + 1] += c00 * bfhi(g00[j]) + c01 * bfhi(g01[j]) + c10 * bfhi(g10[j]) + c11 * bfhi(g11[j]);
      }
    }
    bfr8 r;
#pragma unroll
    for (int j = 0; j < 8; ++j) r.u[j] = f2bf(a[j]);
    *(s8v*)(&As[q * KSTR + h * 32 + dg * 8]) = r.s;
  }

  // ---------------- Phase B: out GEMM from LDS A-tile ----------------
  const int lane = tid & 63, wid = tid >> 6;
  const int am = lane & 15, kq = (lane >> 4) * 8, row4 = (lane >> 4) * 4;
  const int o0w = wid * 64;
  const float* Wrow = W_out + (size_t)tid * DIMC;  // one o-row per thread

  float4 wx[8];
#pragma unroll
  for (int c = 0; c < 8; ++c) wx[c] = *(const float4*)(Wrow + c * 4);

  f4 acc[2][4];
#pragma unroll
  for (int mi = 0; mi < 2; ++mi)
#pragma unroll
    for (int oj = 0; oj < 4; ++oj) acc[mi][oj] = (f4)0.f;

  for (int t = 0; t < 8; ++t) {
    __syncthreads();  // t=0: A-tile ready; t>0: prev reads done before rewrite
    {
      const float wt[32] = {wx[0].x, wx[0].y, wx[0].z, wx[0].w,
                            wx[1].x, wx[1].y, wx[1].z, wx[1].w,
                            wx[2].x, wx[2].y, wx[2].z, wx[2].w,
                            wx[3].x, wx[3].y, wx[3].z, wx[3].w,
                            wx[4].x, wx[4].y, wx[4].z, wx[4].w,
                            wx[5].x, wx[5].y, wx[5].z, wx[5].w,
                            wx[6].x, wx[6].y, wx[6].z, wx[6].w,
                            wx[7].x, wx[7].y, wx[7].z, wx[7].w};
      bfr8 pk[4];
#pragma unroll
      for (int g = 0; g < 4; ++g)
#pragma unroll
        for (int j = 0; j < 8; ++j) pk[g].u[j] = f2bf(wt[g * 8 + j]);
#pragma unroll
      for (int g = 0; g < 4; ++g)
        *(s8v*)(&Ws[tid * LSTR + g * 8]) = pk[g].s;
    }
    if (t < 7) {
      const int k0 = (t + 1) * 32;
#pragma unroll
      for (int c = 0; c < 8; ++c) wx[c] = *(const float4*)(Wrow + k0 + c * 4);
    }
    __syncthreads();
    bf16x8 af[2], bf[4];
#pragma unroll
    for (int mi = 0; mi < 2; ++mi)
      af[mi] = *(const bf16x8*)(&As[(mi * 16 + am) * KSTR + t * 32 + kq]);
#pragma unroll
    for (int oj = 0; oj < 4; ++oj)
      bf[oj] = *(const bf16x8*)(&Ws[(o0w + oj * 16 + am) * LSTR + kq]);
#pragma unroll
    for (int mi = 0; mi < 2; ++mi)
#pragma unroll
      for (int oj = 0; oj < 4; ++oj)
        acc[mi][oj] = __builtin_amdgcn_mfma_f32_16x16x32_bf16(af[mi], bf[oj], acc[mi][oj], 0, 0, 0);
  }
#pragma unroll
  for (int oj = 0; oj < 4; ++oj) {
    const int o = o0w + oj * 16 + am;
    const float bias = b_out[o];
#pragma unroll
    for (int mi = 0; mi < 2; ++mi) {
      const int nb = n0 + mi * 16 + row4;
#pragma unroll
      for (int r = 0; r < 4; ++r)
        out[((size_t)b * NQ + nb + r) * DIMC + o] = acc[mi][oj][r] + bias;
    }
  }
}

extern "C" void kernel_launch(void* const* d_in, const int* in_sizes, int n_in,
                              void* d_out, int out_size, void* d_ws, size_t ws_size,
                              hipStream_t stream) {
  const float* query = (const float*)d_in[0];
  const float* value = (const float*)d_in[1];
  const float* W_loc = (const float*)d_in[2];
  const float* b_loc = (const float*)d_in[3];
  const float* W_att = (const float*)d_in[4];
  const float* b_att = (const float*)d_in[5];
  const float* W_val = (const float*)d_in[6];
  const float* b_val = (const float*)d_in[7];
  const float* W_out = (const float*)d_in[8];
  const float* b_out = (const float*)d_in[9];
  float* out = (float*)d_out;

  float* ws = (float*)d_ws;
  float* loc    = ws;                                     // 4*4096*128 f32
  float* att    = loc + (size_t)BC * NQ * 128;            // 4*4096*64 f32
  ushort* vproj = (ushort*)(att + (size_t)BC * NQ * 64);  // bf16 [b][h][n][d]

  dim3 blk(256);
  k_proj  <<<dim3(NQ / 64, 7, BC), blk, 0, stream>>>(query, value, W_loc, b_loc,
             W_att, b_att, W_val, b_val, loc, att, vproj);
  k_samout<<<dim3(NQ / 32, 1, BC), blk, 0, stream>>>(loc, att, vproj,
             W_out, b_out, out);
}

// Round 11
// 128.431 us; speedup vs baseline: 1.2479x; 1.2479x over previous
//
#include <hip/hip_runtime.h>
#include <hip/hip_bf16.h>
#include <math.h>

#define NQ   4096
#define DIMC 256
#define NHC  8
#define NPC  8
#define HDC  32
#define HC   64
#define WC   64
#define BC   4
#define LSTR 40   // LDS row stride in ushorts (80 B: 16B-aligned)

typedef __bf16 bf16x8 __attribute__((ext_vector_type(8)));
typedef __attribute__((ext_vector_type(4))) float f4;
typedef __attribute__((ext_vector_type(8))) short s8v;

__device__ __forceinline__ ushort f2bf(float f) {
  __hip_bfloat16 h = __float2bfloat16(f);
  union { __hip_bfloat16 h; ushort u; } c; c.h = h; return c.u;
}
__device__ __forceinline__ float bfu2f(ushort u) {
  union { unsigned i; float f; } c; c.i = ((unsigned)u) << 16; return c.f;
}
__device__ __forceinline__ float bflo(unsigned u) {
  union { unsigned i; float f; } c; c.i = u << 16; return c.f;
}
__device__ __forceinline__ float bfhi(unsigned u) {
  union { unsigned i; float f; } c; c.i = u & 0xffff0000u; return c.f;
}

union bfr8 { ushort u[8]; bf16x8 v; s8v s; };

// ---------------------------------------------------------------------------
// k_proj (R8 champion): y in [0,2] -> loc/att projection (split-precision
// bf16 MFMA, 3 passes: hi*hi + lo*hi + hi*lo keeps sampling positions
// fp32-accurate), y in [3,6] -> value projection (plain bf16 MFMA).
// Tile 64n x 64o, BK=32, register-prefetch pipeline. One merged launch so
// the two independent GEMMs co-schedule.
// ---------------------------------------------------------------------------
__global__ __launch_bounds__(256) void k_proj(
    const float* __restrict__ query, const float* __restrict__ value,
    const float* __restrict__ W_loc, const float* __restrict__ b_loc,
    const float* __restrict__ W_att, const float* __restrict__ b_att,
    const float* __restrict__ W_val, const float* __restrict__ b_val,
    float* __restrict__ loc, float* __restrict__ att,
    ushort* __restrict__ vproj) {
  __shared__ __align__(16) ushort smem[4 * 64 * LSTR];  // 20.5 KB
  const int tid = threadIdx.x;
  const int b = blockIdx.z, n0 = blockIdx.x * 64;
  const int lane = tid & 63, wid = tid >> 6;
  const int wn0 = (wid & 1) * 32, wo0 = (wid >> 1) * 32;
  const int am = lane & 15, kq = (lane >> 4) * 8;
  const int an = tid & 63, ak = (tid >> 6) * 8;
  const int wo = tid >> 2, wk = (tid & 3) * 8;

  f4 acc[2][2];
#pragma unroll
  for (int mi = 0; mi < 2; ++mi) { acc[mi][0] = (f4)0.f; acc[mi][1] = (f4)0.f; }

  if (blockIdx.y < 3) {
    // ================= loc/att: split-precision =================
    ushort* Ah = smem;
    ushort* Al = smem + 64 * LSTR;
    ushort* Wh = smem + 2 * 64 * LSTR;
    ushort* Wl = smem + 3 * 64 * LSTR;
    const int o0 = blockIdx.y * 64;
    const float* Xb = query + (size_t)b * DIMC * NQ + n0 + an;
    const int oo = o0 + wo;
    const float* Wrow = (oo < 128) ? (W_loc + (size_t)oo * DIMC)
                                   : (W_att + (size_t)(oo - 128) * DIMC);
    float ax[8];
    float4 wx0, wx1;
#pragma unroll
    for (int j = 0; j < 8; ++j) ax[j] = Xb[(size_t)(ak + j) * NQ];
    wx0 = *(const float4*)(Wrow + wk);
    wx1 = *(const float4*)(Wrow + wk + 4);

    for (int t = 0; t < 8; ++t) {
      __syncthreads();
      {
        bfr8 ph, pl;
#pragma unroll
        for (int j = 0; j < 8; ++j) {
          ushort h = f2bf(ax[j]);
          ph.u[j] = h;
          pl.u[j] = f2bf(ax[j] - bfu2f(h));
        }
        *(s8v*)(&Ah[an * LSTR + ak]) = ph.s;
        *(s8v*)(&Al[an * LSTR + ak]) = pl.s;
        float wt[8] = {wx0.x, wx0.y, wx0.z, wx0.w, wx1.x, wx1.y, wx1.z, wx1.w};
        bfr8 qh, ql;
#pragma unroll
        for (int j = 0; j < 8; ++j) {
          ushort h = f2bf(wt[j]);
          qh.u[j] = h;
          ql.u[j] = f2bf(wt[j] - bfu2f(h));
        }
        *(s8v*)(&Wh[wo * LSTR + wk]) = qh.s;
        *(s8v*)(&Wl[wo * LSTR + wk]) = ql.s;
      }
      if (t < 7) {
        const int k0 = (t + 1) * 32;
#pragma unroll
        for (int j = 0; j < 8; ++j) ax[j] = Xb[(size_t)(k0 + ak + j) * NQ];
        wx0 = *(const float4*)(Wrow + k0 + wk);
        wx1 = *(const float4*)(Wrow + k0 + wk + 4);
      }
      __syncthreads();
      bf16x8 ah[2], al[2], bh[2], bl[2];
#pragma unroll
      for (int mi = 0; mi < 2; ++mi) {
        ah[mi] = *(const bf16x8*)(&Ah[(wn0 + mi * 16 + am) * LSTR + kq]);
        al[mi] = *(const bf16x8*)(&Al[(wn0 + mi * 16 + am) * LSTR + kq]);
      }
#pragma unroll
      for (int oj = 0; oj < 2; ++oj) {
        bh[oj] = *(const bf16x8*)(&Wh[(wo0 + oj * 16 + am) * LSTR + kq]);
        bl[oj] = *(const bf16x8*)(&Wl[(wo0 + oj * 16 + am) * LSTR + kq]);
      }
#pragma unroll
      for (int mi = 0; mi < 2; ++mi)
#pragma unroll
        for (int oj = 0; oj < 2; ++oj) {
          acc[mi][oj] = __builtin_amdgcn_mfma_f32_16x16x32_bf16(ah[mi], bh[oj], acc[mi][oj], 0, 0, 0);
          acc[mi][oj] = __builtin_amdgcn_mfma_f32_16x16x32_bf16(al[mi], bh[oj], acc[mi][oj], 0, 0, 0);
          acc[mi][oj] = __builtin_amdgcn_mfma_f32_16x16x32_bf16(ah[mi], bl[oj], acc[mi][oj], 0, 0, 0);
        }
    }
    const bool isAtt = (o0 >= 128);
    float* dstBase = isAtt ? att : loc;
    const float* bias = isAtt ? b_att : b_loc;
    const int ostride = isAtt ? 64 : 128;
    const int ob = isAtt ? o0 - 128 : o0;
#pragma unroll
    for (int oj = 0; oj < 2; ++oj) {
      const int o = ob + wo0 + oj * 16 + am;
      const float bv = bias[o];
#pragma unroll
      for (int mi = 0; mi < 2; ++mi) {
        const int nb = n0 + wn0 + mi * 16 + (lane >> 4) * 4;
#pragma unroll
        for (int r = 0; r < 4; ++r)
          dstBase[((size_t)b * NQ + nb + r) * ostride + o] = acc[mi][oj][r] + bv;
      }
    }
  } else {
    // ================= value projection =================
    ushort* As = smem;
    ushort* Ws = smem + 64 * LSTR;
    const int o0 = (blockIdx.y - 3) * 64;
    const float* Xb = value + (size_t)b * DIMC * NQ + n0 + an;
    const float* Wrow = W_val + (size_t)(o0 + wo) * DIMC;

    float ax[8];
    float4 wx0, wx1;
#pragma unroll
    for (int j = 0; j < 8; ++j) ax[j] = Xb[(size_t)(ak + j) * NQ];
    wx0 = *(const float4*)(Wrow + wk);
    wx1 = *(const float4*)(Wrow + wk + 4);

    for (int t = 0; t < 8; ++t) {
      __syncthreads();
      {
        bfr8 pa;
#pragma unroll
        for (int j = 0; j < 8; ++j) pa.u[j] = f2bf(ax[j]);
        *(s8v*)(&As[an * LSTR + ak]) = pa.s;
        float wt[8] = {wx0.x, wx0.y, wx0.z, wx0.w, wx1.x, wx1.y, wx1.z, wx1.w};
        bfr8 pw;
#pragma unroll
        for (int j = 0; j < 8; ++j) pw.u[j] = f2bf(wt[j]);
        *(s8v*)(&Ws[wo * LSTR + wk]) = pw.s;
      }
      if (t < 7) {
        const int k0 = (t + 1) * 32;
#pragma unroll
        for (int j = 0; j < 8; ++j) ax[j] = Xb[(size_t)(k0 + ak + j) * NQ];
        wx0 = *(const float4*)(Wrow + k0 + wk);
        wx1 = *(const float4*)(Wrow + k0 + wk + 4);
      }
      __syncthreads();
      bf16x8 af[2], bf[2];
#pragma unroll
      for (int mi = 0; mi < 2; ++mi)
        af[mi] = *(const bf16x8*)(&As[(wn0 + mi * 16 + am) * LSTR + kq]);
#pragma unroll
      for (int oj = 0; oj < 2; ++oj)
        bf[oj] = *(const bf16x8*)(&Ws[(wo0 + oj * 16 + am) * LSTR + kq]);
#pragma unroll
      for (int mi = 0; mi < 2; ++mi)
#pragma unroll
        for (int oj = 0; oj < 2; ++oj)
          acc[mi][oj] = __builtin_amdgcn_mfma_f32_16x16x32_bf16(af[mi], bf[oj], acc[mi][oj], 0, 0, 0);
    }
#pragma unroll
    for (int oj = 0; oj < 2; ++oj) {
      const int o = o0 + wo0 + oj * 16 + am;
      const int h = o >> 5, d = o & 31;
      const float bias = b_val[o];
      ushort* dst = vproj + ((size_t)(b * NHC + h) * NQ) * HDC + d;
#pragma unroll
      for (int mi = 0; mi < 2; ++mi) {
        const int nb = n0 + wn0 + mi * 16 + (lane >> 4) * 4;
#pragma unroll
        for (int r = 0; r < 4; ++r)
          dst[(size_t)(nb + r) * HDC] = f2bf(acc[mi][oj][r] + bias);
      }
    }
  }
}

// ---------------------------------------------------------------------------
// Sampling (R8 champion): Phase A softmax+coefs once per (q,p) into LDS;
// Phase B uint4 (8 bf16 ch) gathers. 64 queries/block — small LDS keeps
// ~8 blocks/CU so gather latency is hidden by TLP (the R10 fusion proved
// this occupancy is load-bearing).
// ---------------------------------------------------------------------------
__global__ __launch_bounds__(256) void k_sample(
    const float* __restrict__ loc, const float* __restrict__ attL,
    const ushort* __restrict__ vproj, ushort* __restrict__ msda) {
  __shared__ float4 Lc[64][9];
  __shared__ int4   Lo[64][9];
  const int b = blockIdx.z, h = blockIdx.y;
  const int tid = threadIdx.x;
  const int n0 = blockIdx.x * 64;
#pragma unroll
  for (int it = 0; it < 2; ++it) {
    const int idx = it * 256 + tid;
    const int q = idx >> 3, p = idx & 7;
    const int n = n0 + q;
    const float lg = attL[((size_t)b * NQ + n) * 64 + h * 8 + p];
    float m = lg;
#pragma unroll
    for (int off = 1; off < 8; off <<= 1) m = fmaxf(m, __shfl_xor(m, off, 64));
    const float e = __expf(lg - m);
    float s = e;
#pragma unroll
    for (int off = 1; off < 8; off <<= 1) s += __shfl_xor(s, off, 64);
    const float w = e / s;
    const float2 xy = *(const float2*)(loc + ((size_t)b * NQ + n) * 128 + h * 16 + p * 2);
    const float x = xy.x * 64.0f - 0.5f;
    const float y = xy.y * 64.0f - 0.5f;
    const float x0f = floorf(x), y0f = floorf(y);
    const float wx = x - x0f, wy = y - y0f;
    const int x0 = (int)x0f, y0 = (int)y0f;
    const int x1 = x0 + 1, y1 = y0 + 1;
    const float fx0 = (x0 >= 0 && x0 < WC) ? 1.f : 0.f;
    const float fx1 = (x1 >= 0 && x1 < WC) ? 1.f : 0.f;
    const float fy0 = (y0 >= 0 && y0 < HC) ? 1.f : 0.f;
    const float fy1 = (y1 >= 0 && y1 < HC) ? 1.f : 0.f;
    const int cx0 = min(max(x0, 0), WC - 1), cx1 = min(max(x1, 0), WC - 1);
    const int cy0 = min(max(y0, 0), HC - 1), cy1 = min(max(y1, 0), HC - 1);
    float4 cf;
    cf.x = w * (1.f - wx) * (1.f - wy) * fx0 * fy0;
    cf.y = w * wx * (1.f - wy) * fx1 * fy0;
    cf.z = w * (1.f - wx) * wy * fx0 * fy1;
    cf.w = w * wx * wy * fx1 * fy1;
    int4 of;
    of.x = (cy0 * WC + cx0) * HDC; of.y = (cy0 * WC + cx1) * HDC;
    of.z = (cy1 * WC + cx0) * HDC; of.w = (cy1 * WC + cx1) * HDC;
    Lc[q][p] = cf; Lo[q][p] = of;
  }
  __syncthreads();
  const int q = tid >> 2, d8 = (tid & 3) * 8;
  const int n = n0 + q;
  const ushort* vb = vproj + (size_t)((b * NHC + h) * NQ) * HDC + d8;
  float a[8] = {};
#pragma unroll
  for (int p = 0; p < 8; ++p) {
    const int4 of = Lo[q][p];
    const float4 cf = Lc[q][p];
    const uint4 u00 = *(const uint4*)(vb + of.x);
    const uint4 u01 = *(const uint4*)(vb + of.y);
    const uint4 u10 = *(const uint4*)(vb + of.z);
    const uint4 u11 = *(const uint4*)(vb + of.w);
    const unsigned c00[4] = {u00.x, u00.y, u00.z, u00.w};
    const unsigned c01[4] = {u01.x, u01.y, u01.z, u01.w};
    const unsigned c10[4] = {u10.x, u10.y, u10.z, u10.w};
    const unsigned c11[4] = {u11.x, u11.y, u11.z, u11.w};
#pragma unroll
    for (int j = 0; j < 4; ++j) {
      a[2 * j]     += cf.x * bflo(c00[j]) + cf.y * bflo(c01[j]) + cf.z * bflo(c10[j]) + cf.w * bflo(c11[j]);
      a[2 * j + 1] += cf.x * bfhi(c00[j]) + cf.y * bfhi(c01[j]) + cf.z * bfhi(c10[j]) + cf.w * bfhi(c11[j]);
    }
  }
  bfr8 r;
#pragma unroll
  for (int j = 0; j < 8; ++j) r.u[j] = f2bf(a[j]);
  *(s8v*)(msda + ((size_t)b * NQ + n) * DIMC + h * HDC + d8) = r.s;
}

// ---------------------------------------------------------------------------
// GEMM 3 (R8 champion): out = msda @ W_out^T + b_out. 64n x 64o, BK=32
// register-prefetch pipeline.
// ---------------------------------------------------------------------------
__global__ __launch_bounds__(256) void k_out(
    const ushort* __restrict__ msda, const float* __restrict__ W_out,
    const float* __restrict__ b_out, float* __restrict__ out) {
  __shared__ __align__(16) ushort As[64 * LSTR];
  __shared__ __align__(16) ushort Ws[64 * LSTR];
  const int b = blockIdx.z, n0 = blockIdx.x * 64, o0 = blockIdx.y * 64;
  const int tid = threadIdx.x, lane = tid & 63, wid = tid >> 6;
  const int wn0 = (wid & 1) * 32, wo0 = (wid >> 1) * 32;
  const int am = lane & 15, kq = (lane >> 4) * 8;
  const int ar = tid >> 2, akq = (tid & 3) * 8;
  const int wo = tid >> 2, wk = (tid & 3) * 8;
  const ushort* Ab = msda + ((size_t)b * NQ + n0 + ar) * DIMC + akq;
  const float* Wrow = W_out + (size_t)(o0 + wo) * DIMC;

  f4 acc[2][2];
#pragma unroll
  for (int mi = 0; mi < 2; ++mi) { acc[mi][0] = (f4)0.f; acc[mi][1] = (f4)0.f; }

  s8v aval = *(const s8v*)(Ab);
  float4 wx0 = *(const float4*)(Wrow + wk);
  float4 wx1 = *(const float4*)(Wrow + wk + 4);

  for (int t = 0; t < 8; ++t) {
    __syncthreads();
    *(s8v*)(&As[ar * LSTR + akq]) = aval;
    {
      float wt[8] = {wx0.x, wx0.y, wx0.z, wx0.w, wx1.x, wx1.y, wx1.z, wx1.w};
      bfr8 pw;
#pragma unroll
      for (int j = 0; j < 8; ++j) pw.u[j] = f2bf(wt[j]);
      *(s8v*)(&Ws[wo * LSTR + wk]) = pw.s;
    }
    if (t < 7) {
      const int k0 = (t + 1) * 32;
      aval = *(const s8v*)(Ab + k0);
      wx0 = *(const float4*)(Wrow + k0 + wk);
      wx1 = *(const float4*)(Wrow + k0 + wk + 4);
    }
    __syncthreads();
    bf16x8 af[2], bf[2];
#pragma unroll
    for (int mi = 0; mi < 2; ++mi)
      af[mi] = *(const bf16x8*)(&As[(wn0 + mi * 16 + am) * LSTR + kq]);
#pragma unroll
    for (int oj = 0; oj < 2; ++oj)
      bf[oj] = *(const bf16x8*)(&Ws[(wo0 + oj * 16 + am) * LSTR + kq]);
#pragma unroll
    for (int mi = 0; mi < 2; ++mi)
#pragma unroll
      for (int oj = 0; oj < 2; ++oj)
        acc[mi][oj] = __builtin_amdgcn_mfma_f32_16x16x32_bf16(af[mi], bf[oj], acc[mi][oj], 0, 0, 0);
  }
#pragma unroll
  for (int oj = 0; oj < 2; ++oj) {
    const int o = o0 + wo0 + oj * 16 + am;
    const float bias = b_out[o];
#pragma unroll
    for (int mi = 0; mi < 2; ++mi) {
      const int nb = n0 + wn0 + mi * 16 + (lane >> 4) * 4;
#pragma unroll
      for (int r = 0; r < 4; ++r)
        out[((size_t)b * NQ + nb + r) * DIMC + o] = acc[mi][oj][r] + bias;
    }
  }
}

extern "C" void kernel_launch(void* const* d_in, const int* in_sizes, int n_in,
                              void* d_out, int out_size, void* d_ws, size_t ws_size,
                              hipStream_t stream) {
  const float* query = (const float*)d_in[0];
  const float* value = (const float*)d_in[1];
  const float* W_loc = (const float*)d_in[2];
  const float* b_loc = (const float*)d_in[3];
  const float* W_att = (const float*)d_in[4];
  const float* b_att = (const float*)d_in[5];
  const float* W_val = (const float*)d_in[6];
  const float* b_val = (const float*)d_in[7];
  const float* W_out = (const float*)d_in[8];
  const float* b_out = (const float*)d_in[9];
  float* out = (float*)d_out;

  float* ws = (float*)d_ws;
  float* loc    = ws;                                     // 4*4096*128 f32
  float* att    = loc + (size_t)BC * NQ * 128;            // 4*4096*64 f32
  ushort* vproj = (ushort*)(att + (size_t)BC * NQ * 64);  // bf16 [b][h][n][d]
  ushort* msda  = vproj + (size_t)BC * NHC * NQ * HDC;    // bf16 [b][n][256]

  dim3 blk(256);
  k_proj  <<<dim3(NQ / 64, 7, BC), blk, 0, stream>>>(query, value, W_loc, b_loc,
             W_att, b_att, W_val, b_val, loc, att, vproj);
  k_sample<<<dim3(NQ / 64, NHC, BC), blk, 0, stream>>>(loc, att, vproj, msda);
  k_out   <<<dim3(NQ / 64, 4, BC), blk, 0, stream>>>(msda, W_out, b_out, out);
}